// Round 6
// baseline (84.712 us; speedup 1.0000x reference)
//
#include <hip/hip_runtime.h>

#define BS 4
#define DM 1024
#define LL 2048
#define NS 64
#define CC 32        // chunks; s = CC*BS*NS*DM*4 = 32 MB (fits ws; L3-resident)
#define TC 64        // chunk length = LL/CC
#define ROWS 64      // d-rows per block; 128-thread blocks = 64 d x 2 lanes
#define PADS 65      // odd stride -> bank (dl+t)%32, conflict-free
#define NSG 32       // states per lane (lane&1 picks half)

// ---------------- pass 1: chunk-local final states (zero init) ----------------
// waves_per_eu(4,4): scheduler targets exactly 4 waves/EU -> 128-reg budget,
// no incentive to spill a[]/g[] (round-5 bug: it chased 8 waves/EU -> 64 regs).
__global__ __launch_bounds__(128) __attribute__((amdgpu_waves_per_eu(4, 4)))
void ssm_pass1(const float* __restrict__ u, const float* __restrict__ A,
               float* __restrict__ s) {
    __shared__ float tile[ROWS * PADS];
    const int tid = threadIdx.x;
    const int bx  = blockIdx.x;
    const int c   = bx & (CC - 1);
    const int rem = bx >> 5;
    const int b   = rem & (BS - 1);
    const int d0  = (rem >> 2) * ROWS;
    const int dl  = tid >> 1;      // d-row within block (0..63)
    const int grp = tid & 1;       // state half
    const int ib  = NSG * grp;

    // stage u tile (64 x 64): float4 coalesced
    {
        const float* ubase = u + ((size_t)(b * DM + d0) * LL + c * TC);
#pragma unroll
        for (int k = 0; k < 8; ++k) {
            const int idx = tid + k * 128;
            const int r   = idx >> 4;
            const int t4  = (idx & 15) * 4;
            const float4 v = *reinterpret_cast<const float4*>(ubase + (size_t)r * LL + t4);
            float* dst = &tile[r * PADS + t4];
            dst[0] = v.x; dst[1] = v.y; dst[2] = v.z; dst[3] = v.w;
        }
    }

    // divergent (grp-dependent) param loads -> per-lane values, VGPR-resident
    float a[NSG];
#pragma unroll
    for (int j = 0; j < NSG; ++j) a[j] = A[(ib + j) * (NS + 1)];

    float g[NSG];
#pragma unroll
    for (int j = 0; j < NSG; ++j) g[j] = 0.f;

    __syncthreads();

    const float* row = &tile[dl * PADS];
#pragma unroll 4
    for (int t = 0; t < TC; ++t) {
        const float uv = row[t];
#pragma unroll
        for (int j = 0; j < NSG; ++j) g[j] = fmaf(a[j], g[j], uv);
    }

    const int d = d0 + dl;
#pragma unroll
    for (int j = 0; j < NSG; ++j)
        s[(((size_t)c * BS + b) * NS + ib + j) * DM + d] = g[j];
}

// ---------------- combine: prefetch-all, scan in-register, store-all ----------------
__global__ __launch_bounds__(256) __attribute__((amdgpu_waves_per_eu(4, 4)))
void ssm_combine(const float* __restrict__ A, float* __restrict__ s) {
    const int tid = blockIdx.x * blockDim.x + threadIdx.x;  // B*N*D threads
    const int d   = tid & (DM - 1);
    const int rem = tid >> 10;
    const int i   = rem & (NS - 1);
    const int b   = rem >> 6;

    const float a = A[i * (NS + 1)];
    float aT = a;                  // a^TC, TC=64 -> 6 squarings
#pragma unroll
    for (int j = 0; j < 6; ++j) aT *= aT;

    const size_t base    = ((size_t)b * NS + i) * DM + d;
    const size_t cstride = (size_t)BS * NS * DM;

    // all 32 loads independent -> one latency exposure
    float v[CC];
#pragma unroll
    for (int c = 0; c < CC; ++c) v[c] = s[base + (size_t)c * cstride];

    float run = 0.f;
#pragma unroll
    for (int c = 0; c < CC; ++c) {
        const float sl = v[c];
        s[base + (size_t)c * cstride] = run;   // true initial state of chunk c
        run = fmaf(aT, run, sl);
    }
}

// ---------------- pass 2: recurrence with true init, produce y ----------------
// waves_per_eu(3,3): 170-reg budget for ~120 live floats (a32+w32+g32+misc).
__global__ __launch_bounds__(128) __attribute__((amdgpu_waves_per_eu(3, 3)))
void ssm_pass2(const float* __restrict__ u, const float* __restrict__ A,
               const float* __restrict__ Bv, const float* __restrict__ Cv,
               const float* __restrict__ s, float* __restrict__ y) {
    __shared__ float tile[ROWS * PADS];
    const int tid = threadIdx.x;
    const int bx  = blockIdx.x;
    const int c   = bx & (CC - 1);
    const int rem = bx >> 5;
    const int b   = rem & (BS - 1);
    const int d0  = (rem >> 2) * ROWS;
    const int dl  = tid >> 1;
    const int grp = tid & 1;
    const int ib  = NSG * grp;

    // stage u tile
    {
        const float* ubase = u + ((size_t)(b * DM + d0) * LL + c * TC);
#pragma unroll
        for (int k = 0; k < 8; ++k) {
            const int idx = tid + k * 128;
            const int r   = idx >> 4;
            const int t4  = (idx & 15) * 4;
            const float4 v = *reinterpret_cast<const float4*>(ubase + (size_t)r * LL + t4);
            float* dst = &tile[r * PADS + t4];
            dst[0] = v.x; dst[1] = v.y; dst[2] = v.z; dst[3] = v.w;
        }
    }

    // divergent param loads -> VGPRs
    float a[NSG], w[NSG];
#pragma unroll
    for (int j = 0; j < NSG; ++j) {
        a[j] = A[(ib + j) * (NS + 1)];
        w[j] = Bv[ib + j] * Cv[ib + j];
    }

    // true chunk-initial states (latency overlaps staging)
    float g[NSG];
    const int d = d0 + dl;
#pragma unroll
    for (int j = 0; j < NSG; ++j)
        g[j] = s[(((size_t)c * BS + b) * NS + ib + j) * DM + d];

    __syncthreads();

    float* row = &tile[dl * PADS];
#pragma unroll 4
    for (int t = 0; t < TC; ++t) {
        const float uv = row[t];
        float y0 = 0.f, y1 = 0.f;
#pragma unroll
        for (int j = 0; j < NSG; j += 2) {
            g[j + 0] = fmaf(a[j + 0], g[j + 0], uv); y0 = fmaf(w[j + 0], g[j + 0], y0);
            g[j + 1] = fmaf(a[j + 1], g[j + 1], uv); y1 = fmaf(w[j + 1], g[j + 1], y1);
        }
        float yp = y0 + y1;
        yp += __shfl_xor(yp, 1, 64);   // combine the two state-halves of this d
        if (grp == 0) row[t] = yp;     // single-lane LDS write
    }
    __syncthreads();

    // coalesced float4 writeout of y
    {
        float* ybase = y + ((size_t)(b * DM + d0) * LL + c * TC);
#pragma unroll
        for (int k = 0; k < 8; ++k) {
            const int idx = tid + k * 128;
            const int r   = idx >> 4;
            const int t4  = (idx & 15) * 4;
            const float* sp = &tile[r * PADS + t4];
            const float4 v = make_float4(sp[0], sp[1], sp[2], sp[3]);
            *reinterpret_cast<float4*>(ybase + (size_t)r * LL + t4) = v;
        }
    }
}

extern "C" void kernel_launch(void* const* d_in, const int* in_sizes, int n_in,
                              void* d_out, int out_size, void* d_ws, size_t ws_size,
                              hipStream_t stream) {
    const float* u  = (const float*)d_in[0];
    const float* A  = (const float*)d_in[1];
    const float* Bv = (const float*)d_in[2];
    const float* Cv = (const float*)d_in[3];
    float* y = (float*)d_out;
    float* s = (float*)d_ws;

    const int nblocks = CC * BS * (DM / ROWS);   // 2048
    ssm_pass1<<<nblocks, 128, 0, stream>>>(u, A, s);
    ssm_combine<<<(BS * NS * DM) / 256, 256, 0, stream>>>(A, s);
    ssm_pass2<<<nblocks, 128, 0, stream>>>(u, A, Bv, Cv, s, y);
}

// Round 7
// 76.286 us; speedup vs baseline: 1.1105x; 1.1105x over previous
//
#include <hip/hip_runtime.h>

#define BS 4
#define DM 1024
#define LL 2048
#define NS 64
#define CC 32        // chunks; s = CC*BS*NS*DM*4 = 32 MB (fits ws; L3-resident)
#define TC 64        // chunk length = LL/CC
#define ROWS 32      // d-rows per block; 128-thread blocks = 32 d x 4 lanes
#define PADS 65      // odd stride -> conflict-free compute reads
#define NSG 16       // states per lane (tid&3 picks quarter)
                     // live set: a16+w16+g16+misc ~58 regs -> fits 64-reg/8-wave target

// ---------------- pass 1: chunk-local final states (zero init) ----------------
__global__ __launch_bounds__(128) void ssm_pass1(const float* __restrict__ u,
                                                 const float* __restrict__ A,
                                                 float* __restrict__ s) {
    __shared__ float tile[ROWS * PADS];
    const int tid = threadIdx.x;
    const int bx  = blockIdx.x;
    const int c   = bx & (CC - 1);
    const int rem = bx >> 5;
    const int b   = rem & (BS - 1);
    const int d0  = (rem >> 2) * ROWS;
    const int dl  = tid >> 2;      // d-row within block (0..31)
    const int grp = tid & 3;       // state quarter
    const int ib  = NSG * grp;

    // stage u tile (32 x 64): 4 float4 per thread, coalesced
    {
        const float* ubase = u + ((size_t)(b * DM + d0) * LL + c * TC);
#pragma unroll
        for (int k = 0; k < 4; ++k) {
            const int idx = tid + k * 128;
            const int r   = idx >> 4;          // 16 float4 per row
            const int t4  = (idx & 15) * 4;
            const float4 v = *reinterpret_cast<const float4*>(ubase + (size_t)r * LL + t4);
            float* dst = &tile[r * PADS + t4];
            dst[0] = v.x; dst[1] = v.y; dst[2] = v.z; dst[3] = v.w;
        }
    }

    // divergent (grp-dependent) param loads -> per-lane VGPR values
    float a[NSG];
#pragma unroll
    for (int j = 0; j < NSG; ++j) a[j] = A[(ib + j) * (NS + 1)];

    float g[NSG];
#pragma unroll
    for (int j = 0; j < NSG; ++j) g[j] = 0.f;

    __syncthreads();

    const float* row = &tile[dl * PADS];
#pragma unroll 2
    for (int t = 0; t < TC; ++t) {
        const float uv = row[t];   // 4-lane same-address -> broadcast, free
#pragma unroll
        for (int j = 0; j < NSG; ++j) g[j] = fmaf(a[j], g[j], uv);
    }

    const int d = d0 + dl;
#pragma unroll
    for (int j = 0; j < NSG; ++j)
        s[(((size_t)c * BS + b) * NS + ib + j) * DM + d] = g[j];
}

// ---------------- combine: prefetch-all, scan in-register, store-all ----------------
__global__ __launch_bounds__(256) void ssm_combine(const float* __restrict__ A,
                                                   float* __restrict__ s) {
    const int tid = blockIdx.x * blockDim.x + threadIdx.x;  // B*N*D threads
    const int d   = tid & (DM - 1);
    const int rem = tid >> 10;
    const int i   = rem & (NS - 1);
    const int b   = rem >> 6;

    const float a = A[i * (NS + 1)];
    float aT = a;                  // a^TC, TC=64 -> 6 squarings
#pragma unroll
    for (int j = 0; j < 6; ++j) aT *= aT;

    const size_t base    = ((size_t)b * NS + i) * DM + d;
    const size_t cstride = (size_t)BS * NS * DM;

    // 32 independent loads -> one latency exposure (v[32]+misc ~45 regs, fits)
    float v[CC];
#pragma unroll
    for (int c = 0; c < CC; ++c) v[c] = s[base + (size_t)c * cstride];

    float run = 0.f;
#pragma unroll
    for (int c = 0; c < CC; ++c) {
        const float sl = v[c];
        s[base + (size_t)c * cstride] = run;   // true initial state of chunk c
        run = fmaf(aT, run, sl);
    }
}

// ---------------- pass 2: recurrence with true init, produce y ----------------
__global__ __launch_bounds__(128) void ssm_pass2(const float* __restrict__ u,
                                                 const float* __restrict__ A,
                                                 const float* __restrict__ Bv,
                                                 const float* __restrict__ Cv,
                                                 const float* __restrict__ s,
                                                 float* __restrict__ y) {
    __shared__ float tile[ROWS * PADS];
    const int tid = threadIdx.x;
    const int bx  = blockIdx.x;
    const int c   = bx & (CC - 1);
    const int rem = bx >> 5;
    const int b   = rem & (BS - 1);
    const int d0  = (rem >> 2) * ROWS;
    const int dl  = tid >> 2;
    const int grp = tid & 3;
    const int ib  = NSG * grp;

    // stage u tile
    {
        const float* ubase = u + ((size_t)(b * DM + d0) * LL + c * TC);
#pragma unroll
        for (int k = 0; k < 4; ++k) {
            const int idx = tid + k * 128;
            const int r   = idx >> 4;
            const int t4  = (idx & 15) * 4;
            const float4 v = *reinterpret_cast<const float4*>(ubase + (size_t)r * LL + t4);
            float* dst = &tile[r * PADS + t4];
            dst[0] = v.x; dst[1] = v.y; dst[2] = v.z; dst[3] = v.w;
        }
    }

    // divergent param loads -> VGPRs (16+16 values)
    float a[NSG], w[NSG];
#pragma unroll
    for (int j = 0; j < NSG; ++j) {
        a[j] = A[(ib + j) * (NS + 1)];
        w[j] = Bv[ib + j] * Cv[ib + j];
    }

    // true chunk-initial states (latency overlaps staging)
    float g[NSG];
    const int d = d0 + dl;
#pragma unroll
    for (int j = 0; j < NSG; ++j)
        g[j] = s[(((size_t)c * BS + b) * NS + ib + j) * DM + d];

    __syncthreads();

    float* row = &tile[dl * PADS];
#pragma unroll 2
    for (int t = 0; t < TC; ++t) {
        const float uv = row[t];
        float y0 = 0.f, y1 = 0.f;
#pragma unroll
        for (int j = 0; j < NSG; j += 2) {
            g[j + 0] = fmaf(a[j + 0], g[j + 0], uv); y0 = fmaf(w[j + 0], g[j + 0], y0);
            g[j + 1] = fmaf(a[j + 1], g[j + 1], uv); y1 = fmaf(w[j + 1], g[j + 1], y1);
        }
        float yp = y0 + y1;
        yp += __shfl_xor(yp, 1, 64);   // combine 4 state-quarters of this d
        yp += __shfl_xor(yp, 2, 64);
        if (grp == 0) row[t] = yp;     // single-lane LDS write per d
    }
    __syncthreads();

    // coalesced float4 writeout of y
    {
        float* ybase = y + ((size_t)(b * DM + d0) * LL + c * TC);
#pragma unroll
        for (int k = 0; k < 4; ++k) {
            const int idx = tid + k * 128;
            const int r   = idx >> 4;
            const int t4  = (idx & 15) * 4;
            const float* sp = &tile[r * PADS + t4];
            const float4 v = make_float4(sp[0], sp[1], sp[2], sp[3]);
            *reinterpret_cast<float4*>(ybase + (size_t)r * LL + t4) = v;
        }
    }
}

extern "C" void kernel_launch(void* const* d_in, const int* in_sizes, int n_in,
                              void* d_out, int out_size, void* d_ws, size_t ws_size,
                              hipStream_t stream) {
    const float* u  = (const float*)d_in[0];
    const float* A  = (const float*)d_in[1];
    const float* Bv = (const float*)d_in[2];
    const float* Cv = (const float*)d_in[3];
    float* y = (float*)d_out;
    float* s = (float*)d_ws;

    const int nblocks = CC * BS * (DM / ROWS);   // 4096
    ssm_pass1<<<nblocks, 128, 0, stream>>>(u, A, s);
    ssm_combine<<<(BS * NS * DM) / 256, 256, 0, stream>>>(A, s);
    ssm_pass2<<<nblocks, 128, 0, stream>>>(u, A, Bv, Cv, s, y);
}

// Round 8
// 59.847 us; speedup vs baseline: 1.4155x; 1.2747x over previous
//
#include <hip/hip_runtime.h>

#define BS 4
#define DM 1024
#define LL 2048
#define NS 64
#define NCH 16        // chunks per d-row (one per lane quad)
#define TCL 128       // chunk length = LL/NCH
#define CPAD 132      // padded chunk stride (floats): 16B-aligned, banks 4c+t -> <=2-way (free)
#define RSTR (NCH * CPAD)   // 2112 floats per d-row
#define DPB 4         // d-rows per block = 4 waves of 64
#define NSG 16        // states per lane (grp = lane&3 picks quarter)

// DPP quad_perm cross-lane add: pure VALU, no DS pipe.
__device__ __forceinline__ float dpp_add_xor1(float v) {  // lane ^ 1 within quad
    int r = __builtin_amdgcn_update_dpp(0, __float_as_int(v), 0xB1, 0xF, 0xF, true);
    return v + __int_as_float(r);
}
__device__ __forceinline__ float dpp_add_xor2(float v) {  // lane ^ 2 within quad
    int r = __builtin_amdgcn_update_dpp(0, __float_as_int(v), 0x4E, 0xF, 0xF, true);
    return v + __int_as_float(r);
}

__global__ __launch_bounds__(256, 4) void ssm_fused(const float* __restrict__ u,
                                                    const float* __restrict__ A,
                                                    const float* __restrict__ Bv,
                                                    const float* __restrict__ Cv,
                                                    float* __restrict__ y) {
    __shared__ float uS[DPB * RSTR];       // 33792 B -> 4 blocks/CU
    const int tid  = threadIdx.x;
    const int bx   = blockIdx.x;           // 1024 blocks = BS * DM/DPB
    const int b    = bx >> 8;
    const int d0   = (bx & 255) * DPB;
    const int dl   = tid >> 6;             // wave id = d-row within block
    const int lane = tid & 63;
    const int ch   = lane >> 2;            // chunk 0..15
    const int grp  = lane & 3;             // state quarter
    const int ib   = NSG * grp;

    // ---- stage u (DPB rows x LL) into LDS once, float4 both sides ----
    {
        const float* ubase = u + (size_t)(b * DM + d0) * LL;
#pragma unroll
        for (int k = 0; k < 8; ++k) {
            const int idx = tid + k * 256;          // 0..2047 float4 slots
            const int r   = idx >> 9;               // d-row 0..3
            const int t4  = (idx & 511) * 4;        // 0..2044
            const int c4  = t4 >> 7;                // chunk
            const int tin = t4 & 127;
            const float4 v = *reinterpret_cast<const float4*>(ubase + (size_t)r * LL + t4);
            *reinterpret_cast<float4*>(&uS[r * RSTR + c4 * CPAD + tin]) = v;
        }
    }

    // ---- params (divergent per-grp addresses -> VGPR-resident) ----
    float a[NSG], w[NSG];
#pragma unroll
    for (int j = 0; j < NSG; ++j) {
        a[j] = A[(ib + j) * (NS + 1)];
        w[j] = Bv[ib + j] * Cv[ib + j];
    }

    __syncthreads();

    const int rb = dl * RSTR + ch * CPAD;  // my chunk's base in LDS

    // ---- phase A: chunk-local end states (zero init), float4 LDS reads ----
    float g[NSG];
#pragma unroll
    for (int j = 0; j < NSG; ++j) g[j] = 0.f;
    {
        for (int tq = 0; tq < TCL / 4; ++tq) {
            const float4 u4 = *reinterpret_cast<const float4*>(&uS[rb + tq * 4]);
            const float* up = reinterpret_cast<const float*>(&u4);
#pragma unroll
            for (int e = 0; e < 4; ++e) {
                const float uv = up[e];
#pragma unroll
                for (int j = 0; j < NSG; ++j) g[j] = fmaf(a[j], g[j], uv);
            }
        }
    }

    // ---- in-wave combine: inclusive Hillis-Steele scan across chunks, then shift ----
    // H[c] = sum_{c'<=c} (a^TCL)^(c-c') hloc[c'];  h_init[c] = H[c-1]
    {
        float m[NSG];
#pragma unroll
        for (int j = 0; j < NSG; ++j) {
            float x = a[j];
#pragma unroll
            for (int q = 0; q < 7; ++q) x = x * x;   // a^128
            m[j] = x;
        }
#pragma unroll
        for (int k = 0; k < 4; ++k) {
            const int off = 4 << k;                  // 2^k chunks = 4*2^k lanes
            const int src = (lane >= off) ? (lane - off) : 0;
            const bool ok = lane >= off;
#pragma unroll
            for (int j = 0; j < NSG; ++j) {
                const float h = __shfl(g[j], src, 64);
                g[j] = fmaf(ok ? m[j] : 0.0f, h, g[j]);
                m[j] = m[j] * m[j];
            }
        }
        const int src = (lane >= 4) ? (lane - 4) : 0;
#pragma unroll
        for (int j = 0; j < NSG; ++j) {
            const float h = __shfl(g[j], src, 64);
            g[j] = (ch == 0) ? 0.0f : h;             // exclusive: true chunk-initial state
        }
    }

    // ---- phase B: rescan with true init, produce y; DPP reduce; float4 y into LDS ----
    {
        for (int tq = 0; tq < TCL / 4; ++tq) {
            const float4 u4 = *reinterpret_cast<const float4*>(&uS[rb + tq * 4]);
            const float* up = reinterpret_cast<const float*>(&u4);
            float y4[4];
#pragma unroll
            for (int e = 0; e < 4; ++e) {
                const float uv = up[e];
                float y0 = 0.f, y1 = 0.f;
#pragma unroll
                for (int j = 0; j < NSG; j += 2) {
                    g[j + 0] = fmaf(a[j + 0], g[j + 0], uv); y0 = fmaf(w[j + 0], g[j + 0], y0);
                    g[j + 1] = fmaf(a[j + 1], g[j + 1], uv); y1 = fmaf(w[j + 1], g[j + 1], y1);
                }
                float yp = y0 + y1;
                yp = dpp_add_xor1(yp);               // quad reduce: 4 state-quarters
                yp = dpp_add_xor2(yp);               // pure VALU, no DS
                y4[e] = yp;
            }
            if (grp == 0)
                *reinterpret_cast<float4*>(&uS[rb + tq * 4]) =
                    make_float4(y4[0], y4[1], y4[2], y4[3]);
        }
    }

    __syncthreads();

    // ---- coalesced float4 writeout of y ----
    {
        float* ybase = y + (size_t)(b * DM + d0) * LL;
#pragma unroll
        for (int k = 0; k < 8; ++k) {
            const int idx = tid + k * 256;
            const int r   = idx >> 9;
            const int t4  = (idx & 511) * 4;
            const int c4  = t4 >> 7;
            const int tin = t4 & 127;
            const float4 v = *reinterpret_cast<const float4*>(&uS[r * RSTR + c4 * CPAD + tin]);
            *reinterpret_cast<float4*>(ybase + (size_t)r * LL + t4) = v;
        }
    }
}

extern "C" void kernel_launch(void* const* d_in, const int* in_sizes, int n_in,
                              void* d_out, int out_size, void* d_ws, size_t ws_size,
                              hipStream_t stream) {
    const float* u  = (const float*)d_in[0];
    const float* A  = (const float*)d_in[1];
    const float* Bv = (const float*)d_in[2];
    const float* Cv = (const float*)d_in[3];
    float* y = (float*)d_out;

    ssm_fused<<<BS * (DM / DPB), 256, 0, stream>>>(u, A, Bv, Cv, y);
}